// Round 1
// 383.682 us; speedup vs baseline: 1.2617x; 1.2617x over previous
//
#include <hip/hip_runtime.h>
#include <stdint.h>

#define B_TOT 65536

typedef __attribute__((ext_vector_type(8))) short s16x8;
typedef __attribute__((ext_vector_type(4))) float f32x4;
typedef unsigned short u16;
typedef unsigned int u32;

// ---- workspace layout (u16 element offsets), weights in MFMA-fragment order:
//      frag(ct,kt) = [((ct*KT+kt)*64 + lane)*8 + j], n = ct*16+(lane&15), k = kt*32+(lane>>4)*8+j
#define OFF_SKIPW   0         // N=256 K=256 (16ct x 8kt)          65536
#define OFF_MD      65536     // 3 x (N=256 K=256)                 196608
#define OFF_GATEW   262144    // N=48 K=256 (3ct x 8kt)            12288
#define OFF_EXPW1   274432    // 13 x (N=128 K=256)                425984
#define OFF_EXPW2   700416    // 13 x (N=64 K=128)                 106496
#define OFF_DSKIPW  806912    // 6 x (N=64 K=256)                  98304
#define OFF_TOWW1   905216    // 6 x (N=64 K=64)                   24576
#define OFF_BVEC    929792    // 3 x 256 f32                       1536
#define OFF_PAR     931328    // 10240 u16 (bf16 back params)      10240
#define OFF_PARF    941568    // 1536 f32 front params             3072
#define OFF_EMB     944640    // [B/16][8 kt][64][8] bf16 frags = 16777216 u16 (COMPACT)

// back param block layout (u16 element indices within the PAR block)
#define PAR_DSK  7488
#define PAR_TOW  8640
#define PAR_GB   10176
#define PAR_TB2  10224

__device__ __forceinline__ float bf2f(u16 h){ u32 v=((u32)h)<<16; return __builtin_bit_cast(float,v); }
__device__ __forceinline__ u16 f2bf(float f){
  u32 u=__builtin_bit_cast(u32,f);
  u += 0x7fffu + ((u>>16)&1u);
  return (u16)(u>>16);
}
__device__ __forceinline__ f32x4 mfma16(s16x8 a, s16x8 b, f32x4 c){
  return __builtin_amdgcn_mfma_f32_16x16x32_bf16(a,b,c,0,0,0);
}
__device__ __forceinline__ void lds_fence(){ asm volatile("s_waitcnt lgkmcnt(0)" ::: "memory"); }

// async global->LDS staging: wave-striped 1KB units, LDS dest = uniform base + lane*16
__device__ __forceinline__ void gstage(const u16* gsrc, u16* ldsdst, int nbytes, int wv, int lane, int nw){
  for(int off = wv*1024; off < nbytes; off += nw*1024){
    __builtin_amdgcn_global_load_lds(
      (const __attribute__((address_space(1))) u32*)((const char*)gsrc + off + lane*16),
      (__attribute__((address_space(3))) u32*)((char*)ldsdst + off),
      16, 0, 0);
  }
}

template<int NT>
__device__ __forceinline__ void ln16(const f32x4* a, float invN, float* mu, float* rs){
  float s[4], q[4];
#pragma unroll
  for(int r=0;r<4;r++){ float aa=0.f,bb=0.f;
#pragma unroll
    for(int t=0;t<NT;t++){ float v=a[t][r]; aa+=v; bb+=v*v; }
    s[r]=aa; q[r]=bb; }
#pragma unroll
  for(int m=1;m<16;m<<=1){
#pragma unroll
    for(int r=0;r<4;r++){ s[r]+=__shfl_xor(s[r],m,16); q[r]+=__shfl_xor(q[r],m,16); } }
#pragma unroll
  for(int r=0;r<4;r++){ float m_=s[r]*invN; float v=q[r]*invN-m_*m_; mu[r]=m_; rs[r]=rsqrtf(v+1e-5f); }
}

// ============================ pack kernel (weights -> frag layout) ============================
__global__ __launch_bounds__(256) void k_pack(
    const float* __restrict__ skip_W, const float* __restrict__ gate_W,
    const float* __restrict__ exp_W1, const float* __restrict__ dexp_W1, const float* __restrict__ texp_W1,
    const float* __restrict__ exp_W2, const float* __restrict__ dexp_W2, const float* __restrict__ texp_W2,
    const float* __restrict__ dskip_W, const float* __restrict__ tow_W1,
    u16* __restrict__ ws)
{
  int i=blockIdx.x*256+threadIdx.x;
  if(i>=OFF_BVEC) return;
  if(i>=OFF_MD && i<OFF_GATEW) return;   // Md done by k_fold
  float v;
  if(i<OFF_MD){
    int l=i; int j=l&7, lane=(l>>3)&63, kt=(l>>9)&7, ct=l>>12;
    int n=ct*16+(lane&15), k=kt*32+((lane>>4)<<3)+j;
    v = skip_W[k*256+n];
  } else if(i<OFF_EXPW1){
    int l=i-OFF_GATEW; int j=l&7, lane=(l>>3)&63, kt=(l>>9)&7, ct=l>>12;
    int n=ct*16+(lane&15), k=kt*32+((lane>>4)<<3)+j;
    int k6=n>>3, e=n&7;
    v = gate_W[(k6*256+k)*8+e];
  } else if(i<OFF_EXPW2){
    int l=i-OFF_EXPW1; int e=l>>15, r=l&32767;
    int j=r&7, lane=(r>>3)&63, kt=(r>>9)&7, ct=r>>12;
    int n=ct*16+(lane&15), k=kt*32+((lane>>4)<<3)+j;
    v = (e<8)? exp_W1[(e*256+k)*128+n] : (e<11)? dexp_W1[((e-8)*256+k)*128+n] : texp_W1[((e-11)*256+k)*128+n];
  } else if(i<OFF_DSKIPW){
    int l=i-OFF_EXPW2; int e=l>>13, r=l&8191;
    int j=r&7, lane=(r>>3)&63, kt=(r>>9)&3, ct=r>>11;
    int n=ct*16+(lane&15), k=kt*32+((lane>>4)<<3)+j;
    v = (e<8)? exp_W2[(e*128+k)*64+n] : (e<11)? dexp_W2[((e-8)*128+k)*64+n] : texp_W2[((e-11)*128+k)*64+n];
  } else if(i<OFF_TOWW1){
    int l=i-OFF_DSKIPW; int s=l>>14, r=l&16383;
    int j=r&7, lane=(r>>3)&63, kt=(r>>9)&7, ct=r>>12;
    int n=ct*16+(lane&15), k=kt*32+((lane>>4)<<3)+j;
    v = dskip_W[(s*256+k)*64+n];
  } else {
    int l=i-OFF_TOWW1; int s=l>>12, r=l&4095;
    int j=r&7, lane=(r>>3)&63, kt=(r>>9)&1, ct=r>>10;
    int n=ct*16+(lane&15), k=kt*32+((lane>>4)<<3)+j;
    v = tow_W1[(s*64+k)*64+n];
  }
  ws[i]=f2bf(v);
}

// ============================ param pack kernel ====
__global__ __launch_bounds__(256) void k_packpar(
    const float* __restrict__ exp_b1,const float* __restrict__ exp_g1,const float* __restrict__ exp_be1,
    const float* __restrict__ exp_b2,const float* __restrict__ exp_g2,const float* __restrict__ exp_be2,
    const float* __restrict__ dexp_b1,const float* __restrict__ dexp_g1,const float* __restrict__ dexp_be1,
    const float* __restrict__ dexp_b2,const float* __restrict__ dexp_g2,const float* __restrict__ dexp_be2,
    const float* __restrict__ texp_b1,const float* __restrict__ texp_g1,const float* __restrict__ texp_be1,
    const float* __restrict__ texp_b2,const float* __restrict__ texp_g2,const float* __restrict__ texp_be2,
    const float* __restrict__ dskip_b,const float* __restrict__ dskip_g,const float* __restrict__ dskip_be,
    const float* __restrict__ gate_b,
    const float* __restrict__ tow_b1,const float* __restrict__ tow_g,const float* __restrict__ tow_be,
    const float* __restrict__ tow_W2,const float* __restrict__ tow_b2,
    const float* __restrict__ skip_b,const float* __restrict__ skip_g,const float* __restrict__ skip_be,
    const float* __restrict__ star_b,const float* __restrict__ star_g,const float* __restrict__ star_be,
    u16* __restrict__ ws)
{
  int i=blockIdx.x*256+threadIdx.x;
  float* parf=(float*)(ws+OFF_PARF);
  if(i<10240){
    float v=0.f;
    if(i<PAR_DSK){
      int e=i/576, r=i%576;
      const float *b1,*g1,*be1,*b2,*g2,*be2;
      if(e<8){ b1=exp_b1+e*128; g1=exp_g1+e*128; be1=exp_be1+e*128;
               b2=exp_b2+e*64;  g2=exp_g2+e*64;  be2=exp_be2+e*64; }
      else if(e<11){ int q=e-8; b1=dexp_b1+q*128; g1=dexp_g1+q*128; be1=dexp_be1+q*128;
               b2=dexp_b2+q*64; g2=dexp_g2+q*64; be2=dexp_be2+q*64; }
      else { int q=e-11; b1=texp_b1+q*128; g1=texp_g1+q*128; be1=texp_be1+q*128;
               b2=texp_b2+q*64; g2=texp_g2+q*64; be2=texp_be2+q*64; }
      v = (r<128)? b1[r] : (r<256)? g1[r-128] : (r<384)? be1[r-256]
        : (r<448)? b2[r-384] : (r<512)? g2[r-448] : be2[r-512];
    } else if(i<PAR_TOW){
      int l=i-PAR_DSK; int j=l/192, r=l%192;
      v = (r<64)? dskip_b[j*64+r] : (r<128)? dskip_g[j*64+r-64] : dskip_be[j*64+r-128];
    } else if(i<PAR_GB){
      int l=i-PAR_TOW; int k6=l/256, r=l%256;
      v = (r<64)? tow_b1[k6*64+r] : (r<128)? tow_g[k6*64+r-64]
        : (r<192)? tow_be[k6*64+r-128] : tow_W2[k6*64+r-192];
    } else if(i<PAR_TB2){ v=gate_b[i-PAR_GB]; }
    else if(i<PAR_TB2+6){ v=tow_b2[i-PAR_TB2]; }
    ws[OFF_PAR+i]=f2bf(v);
  } else if(i<10240+1536){
    int l=i-10240;
    parf[l] = (l<256)? skip_b[l] : (l<512)? skip_g[l-256] : (l<768)? skip_be[l-512]
            : (l<1024)? star_b[l-768] : (l<1280)? star_g[l-1024] : star_be[l-1280];
  }
}

// ============================ fold kernel ====
__global__ __launch_bounds__(256) void k_fold(
    const float* __restrict__ slot_W, const float* __restrict__ shared_W, const float* __restrict__ star_W,
    const float* __restrict__ slot_b, const float* __restrict__ shared_b,
    u16* __restrict__ ws)
{
  __shared__ float w[512];
  int bid=blockIdx.x, tid=threadIdx.x;
  if(bid<768){
    int d=bid>>8, k=bid&255;
    for(int j=tid;j<512;j+=256) w[j]=slot_W[(d*256+k)*512+j]*shared_W[k*512+j];
    __syncthreads();
    int n=tid; float a=0.f;
    for(int j=0;j<512;j++) a += w[j]*star_W[j*256+n];
    int ct=n>>4, l15=n&15, kt=k>>5, hi=(k>>3)&3, j8=k&7;
    ws[OFF_MD + d*65536 + (((ct*8+kt)*64 + hi*16 + l15)<<3) + j8] = f2bf(a);
  } else {
    int d=bid-768;
    for(int j=tid;j<512;j+=256) w[j]=slot_b[d*512+j]+shared_b[j];
    __syncthreads();
    int n=tid; float a=0.f;
    for(int j=0;j<512;j++) a += w[j]*star_W[j*256+n];
    ((float*)(ws+OFF_BVEC))[d*256+n]=a;
  }
}

// ============================ front kernel ============================
// 256 threads / 128 rows; trb ALIASES Wbuf (skip result round-trips via global emb frags)
__global__ __launch_bounds__(256,2) void k_front(
    const int* __restrict__ x, const float* __restrict__ emb_tables,
    u16* __restrict__ wsu)
{
  __shared__ __align__(16) u16 shbuf[33792];   // trb[4][32][264] ; aliases Wbuf[2][8192]
  __shared__ float bvecL[768];
  __shared__ float parF[1536];

  const int tid=threadIdx.x, lane=tid&63, wv=tid>>6;
  const int l15=lane&15, hq=lane>>4;
  const int b0=blockIdx.x*128, rowbase=b0+wv*32;
  const f32x4 fz={0.f,0.f,0.f,0.f};
  const s16x8 zf={0,0,0,0,0,0,0,0};
  u16* Wb[2]={shbuf, shbuf+8192};
  u16* trbw = shbuf + wv*8448;   // [32][264]
  u16* embp = wsu+OFF_EMB;

  gstage(wsu+OFF_SKIPW, Wb[0], 16384, wv, lane, 4);
  gstage(wsu+OFF_BVEC, (u16*)bvecL, 3072, wv, lane, 4);
  gstage(wsu+OFF_PARF, (u16*)parF, 6144, wv, lane, 4);

  int dmA[2], dm[2][4];
#pragma unroll
  for(int rt=0;rt<2;rt++){
    dmA[rt]=x[15*B_TOT + rowbase + rt*16 + l15];
#pragma unroll
    for(int r=0;r<4;r++) dm[rt][r]=x[15*B_TOT + rowbase + rt*16 + hq*4 + r];
  }

  s16x8 af[2][8];
#pragma unroll
  for(int rt=0;rt<2;rt++){
#pragma unroll
    for(int kt=0;kt<8;kt++){
      int f=kt*2+(hq>>1), j0=(hq&1)*8;
      int row=rowbase+rt*16+l15;
      int idx=x[f*B_TOT+row];
      const float* sp=emb_tables + (size_t)(f*1000+idx)*16 + j0;
      float4 v0=*(const float4*)sp, v1=*(const float4*)(sp+4);
      union{ u16 h[8]; s16x8 v; } t;
      t.h[0]=f2bf(v0.x); t.h[1]=f2bf(v0.y); t.h[2]=f2bf(v0.z); t.h[3]=f2bf(v0.w);
      t.h[4]=f2bf(v1.x); t.h[5]=f2bf(v1.y); t.h[6]=f2bf(v1.z); t.h[7]=f2bf(v1.w);
      af[rt][kt]=t.v;
    }
  }
  __syncthreads();
  int cur=0;

  f32x4 acc[2][16];
#pragma unroll
  for(int rt=0;rt<2;rt++)
#pragma unroll
    for(int ct=0;ct<16;ct++) acc[rt][ct]=fz;

  // ---- skip MLP: 8 chunks (no prefetch at c==7: trb will alias Wbuf) ----
#pragma unroll
  for(int c=0;c<8;c++){
    if(c<7) gstage(wsu+OFF_SKIPW+(c+1)*8192, Wb[cur^1], 16384, wv, lane, 4);
    const u16* B=Wb[cur];
#pragma unroll
    for(int kt=0;kt<8;kt++){
#pragma unroll
      for(int i=0;i<2;i++){
        s16x8 bf=*(const s16x8*)(B + (((i*8+kt)*64+lane)<<3));
        acc[0][c*2+i]=mfma16(af[0][kt],bf,acc[0][c*2+i]);
        acc[1][c*2+i]=mfma16(af[1][kt],bf,acc[1][c*2+i]);
      }
    }
    __syncthreads(); cur^=1;
  }
  // skip epilogue -> trb (aliases Wbuf; safe after barrier, no staging in flight)
#pragma unroll
  for(int rt=0;rt<2;rt++){
#pragma unroll
    for(int ct=0;ct<16;ct++){ float bb=parF[ct*16+l15];
#pragma unroll
      for(int r=0;r<4;r++) acc[rt][ct][r]+=bb; }
    float mu[4],rs[4];
    ln16<16>(&acc[rt][0], 1.f/256.f, mu, rs);
#pragma unroll
    for(int ct=0;ct<16;ct++){
      int col=ct*16+l15;
      float gv=parF[256+col], bev=parF[512+col];
#pragma unroll
      for(int r=0;r<4;r++){
        float v=fmaxf((acc[rt][ct][r]-mu[r])*rs[r]*gv+bev,0.f);
        trbw[(rt*16+hq*4+r)*264 + col]=f2bf(v);
      }
    }
  }
  lds_fence();
  // store skip frags to global emb (read back at the end)
#pragma unroll
  for(int rt=0;rt<2;rt++){
    int rtg=(b0>>4)+wv*2+rt;
#pragma unroll
    for(int kt=0;kt<8;kt++){
      s16x8 v=*(const s16x8*)(trbw + (rt*16+l15)*264 + kt*32+hq*8);
      *(s16x8*)(embp + (((size_t)(rtg*8+kt)*64+lane)<<3)) = v;
    }
  }
  __syncthreads();                       // all trb reads done -> Wbuf reusable
  gstage(wsu+OFF_MD, Wb[0], 16384, wv, lane, 4);
  __syncthreads();
  cur=0;

  // ---- star (folded): sum_d mask_d(x) @ Md ----
#pragma unroll
  for(int rt=0;rt<2;rt++)
#pragma unroll
    for(int ct=0;ct<16;ct++) acc[rt][ct]=fz;
  for(int d=0;d<3;d++){
#pragma unroll
    for(int c=0;c<8;c++){
      if(c<7)      gstage(wsu+OFF_MD+d*65536+(c+1)*8192, Wb[cur^1], 16384, wv, lane, 4);
      else if(d<2) gstage(wsu+OFF_MD+(d+1)*65536,        Wb[cur^1], 16384, wv, lane, 4);
      const u16* B=Wb[cur];
#pragma unroll
      for(int kt=0;kt<8;kt++){
        s16x8 a0=(dmA[0]==d)?af[0][kt]:zf;    // inline mask: no 64-reg hoist
        s16x8 a1=(dmA[1]==d)?af[1][kt]:zf;
#pragma unroll
        for(int i=0;i<2;i++){
          s16x8 bf=*(const s16x8*)(B + (((i*8+kt)*64+lane)<<3));
          acc[0][c*2+i]=mfma16(a0,bf,acc[0][c*2+i]);
          acc[1][c*2+i]=mfma16(a1,bf,acc[1][c*2+i]);
        }
      }
      __syncthreads(); cur^=1;
    }
  }

  // star epilogue -> trb -> + skip frags (global) -> final emb frags
#pragma unroll
  for(int rt=0;rt<2;rt++){
#pragma unroll
    for(int ct=0;ct<16;ct++){
      int col=ct*16+l15; float sb=parF[768+col];
#pragma unroll
      for(int r=0;r<4;r++) acc[rt][ct][r] += sb + bvecL[dm[rt][r]*256+col];
    }
    float mu[4],rs[4];
    ln16<16>(&acc[rt][0], 1.f/256.f, mu, rs);
#pragma unroll
    for(int ct=0;ct<16;ct++){
      int col=ct*16+l15;
      float gv=parF[1024+col], bev=parF[1280+col];
#pragma unroll
      for(int r=0;r<4;r++){
        float v=fmaxf((acc[rt][ct][r]-mu[r])*rs[r]*gv+bev,0.f);
        trbw[(rt*16+hq*4+r)*264 + col]=f2bf(v);
      }
    }
  }
  lds_fence();
#pragma unroll
  for(int rt=0;rt<2;rt++){
    int rtg=(b0>>4)+wv*2+rt;
#pragma unroll
    for(int kt=0;kt<8;kt++){
      s16x8 vs=*(const s16x8*)(trbw + (rt*16+l15)*264 + kt*32+hq*8);
      s16x8 vk=*(const s16x8*)(embp + (((size_t)(rtg*8+kt)*64+lane)<<3));
      union{ u16 h[8]; s16x8 v; } t;
#pragma unroll
      for(int j=0;j<8;j++) t.h[j]=f2bf(bf2f((u16)vs[j])+bf2f((u16)vk[j]));
      *(s16x8*)(embp + (((size_t)(rtg*8+kt)*64+lane)<<3)) = t.v;
    }
  }
}

// ============================ k_B: fused experts + gates + fusion + towers ====
// 512 thr / 8 waves / 256 rows per block. h2 intermediate is GONE: every unit's
// layer-2 (and dskip) output is gate-weighted and accumulated into C-fragment
// registers (fa0/fa1 = the two towers this row's domain needs). Weights stream
// through a 3-slot x 16KB LDS ring, staged 2 phases ahead, with counted
// s_waitcnt vmcnt(2) + raw s_barrier (never drain to 0 mid-loop).
// 82 phases: [0,1]=gates, [2..66]=13 experts x (4xW1 + W2), [67..78]=6 dskip x2,
// [79..81]=towers. Every phase stages exactly 16KB = 2 global_load_lds per wave,
// so vmcnt counting is exact.
__device__ __forceinline__ int phase_off(int p){
  if(p<2)  return OFF_GATEW + p*8192;            // p=1 over-stages 8KB into EXPW1: harmless
  if(p<67){ int q=p-2, u=q/5, s=q%5;
            return (s<4)? (OFF_EXPW1+u*32768+s*8192) : (OFF_EXPW2+u*8192); }
  if(p<79){ int q=p-67; return OFF_DSKIPW + (q>>1)*16384 + (q&1)*8192; }
  return OFF_TOWW1 + (p-79)*8192;
}
__device__ __forceinline__ void stage16k(const u16* g, u16* l, int wv, int lane){
  __builtin_amdgcn_global_load_lds(
    (const __attribute__((address_space(1))) u32*)((const char*)g + wv*1024 + lane*16),
    (__attribute__((address_space(3))) u32*)((char*)l + wv*1024), 16,0,0);
  __builtin_amdgcn_global_load_lds(
    (const __attribute__((address_space(1))) u32*)((const char*)g + 8192 + wv*1024 + lane*16),
    (__attribute__((address_space(3))) u32*)((char*)l + 8192 + wv*1024), 16,0,0);
}
__device__ __forceinline__ void endph2(){ asm volatile("s_waitcnt vmcnt(2)\n\ts_barrier" ::: "memory"); }
__device__ __forceinline__ void endph0(){ asm volatile("s_waitcnt vmcnt(0)\n\ts_barrier" ::: "memory"); }

__global__ __launch_bounds__(512,2) void k_B(
    const int* __restrict__ x, u16* __restrict__ wsu, float* __restrict__ out)
{
  __shared__ __align__(16) u16 Wb[3][8192];        // 48KB ring
  __shared__ __align__(16) u16 trb[8][32][136];    // 68KB per-wave transpose
  __shared__ __align__(16) u16 parAll[10240];      // 20KB all back params
  __shared__ __align__(16) u32 gateF[256][8];      // 8KB (g_T0|g_T1) packed bf16

  const int tid=threadIdx.x, lane=tid&63, wv=tid>>6;
  const int l15=lane&15, hq=lane>>4;
  const int b0=blockIdx.x*256, rowbase=b0+wv*32;
  const f32x4 fz={0.f,0.f,0.f,0.f};
  const u16* embp=wsu+OFF_EMB;
  u16* trbw=&trb[wv][0][0];

  gstage(wsu+OFF_PAR, parAll, 20480, wv, lane, 8);
  stage16k(wsu+phase_off(0), &Wb[0][0], wv, lane);
  stage16k(wsu+phase_off(1), &Wb[1][0], wv, lane);

  int dm[2][4];
#pragma unroll
  for(int rt=0;rt<2;rt++)
#pragma unroll
    for(int r=0;r<4;r++) dm[rt][r]=x[15*B_TOT + rowbase + rt*16 + hq*4 + r];

  s16x8 af[2][8];
#pragma unroll
  for(int rt=0;rt<2;rt++){
    int rtg=(rowbase>>4)+rt;
#pragma unroll
    for(int kt=0;kt<8;kt++)
      af[rt][kt]=*(const s16x8*)(embp + (((size_t)(rtg*8+kt)*64+lane)<<3));
  }

  f32x4 fa0[2][4], fa1[2][4];   // fused accumulators, C-frag layout, T=0 / T=1
#pragma unroll
  for(int rt=0;rt<2;rt++)
#pragma unroll
    for(int ct=0;ct<4;ct++){ fa0[rt][ct]=fz; fa1[rt][ct]=fz; }

  __syncthreads();              // drain prologue loads; phases 0/1 staged
  int p=0;

  // ---- gates (phases 0,1) ----
  {
    f32x4 gacc[2][3];
#pragma unroll
    for(int rt=0;rt<2;rt++)
#pragma unroll
      for(int ct=0;ct<3;ct++) gacc[rt][ct]=fz;
    stage16k(wsu+phase_off(2), &Wb[2][0], wv, lane);
#pragma unroll
    for(int kt=0;kt<8;kt++)
#pragma unroll
      for(int i=0;i<2;i++){
        s16x8 bf=*(const s16x8*)(&Wb[0][0] + (((i*8+kt)*64+lane)<<3));
        gacc[0][i]=mfma16(af[0][kt],bf,gacc[0][i]);
        gacc[1][i]=mfma16(af[1][kt],bf,gacc[1][i]);
      }
    endph2(); p=1;

    stage16k(wsu+phase_off(3), &Wb[0][0], wv, lane);
#pragma unroll
    for(int kt=0;kt<8;kt++){
      s16x8 bf=*(const s16x8*)(&Wb[1][0] + ((kt*64+lane)<<3));
      gacc[0][2]=mfma16(af[0][kt],bf,gacc[0][2]);
      gacc[1][2]=mfma16(af[1][kt],bf,gacc[1][2]);
    }
    u16* gFh=(u16*)&gateF[0][0];
#pragma unroll
    for(int rt=0;rt<2;rt++)
#pragma unroll
      for(int ct=0;ct<3;ct++){
        int k6=ct*2+(l15>>3), e=l15&7;
        float gb=bf2f(parAll[PAR_GB + k6*8+e]);
#pragma unroll
        for(int r=0;r<4;r++){
          float v=gacc[rt][ct][r]+gb;
          float mx=v;
          mx=fmaxf(mx,__shfl_xor(mx,1,8)); mx=fmaxf(mx,__shfl_xor(mx,2,8)); mx=fmaxf(mx,__shfl_xor(mx,4,8));
          float pe=__expf(v-mx);
          float ss=pe;
          ss+=__shfl_xor(ss,1,8); ss+=__shfl_xor(ss,2,8); ss+=__shfl_xor(ss,4,8);
          int brow=wv*32+rt*16+hq*4+r;
          int dmv=dm[rt][r];
          if(k6==dmv)   gFh[(brow*8+e)*2]  =f2bf(pe/ss);
          if(k6==3+dmv) gFh[(brow*8+e)*2+1]=f2bf(pe/ss);
        }
      }
    lds_fence();
    endph2(); p=2;
  }

  // ---- 13 two-layer experts (u<8 exp, 8..10 dexp, 11..12 texp) ----
  for(int u=0;u<13;u++){
    f32x4 acc1[2][8];
#pragma unroll
    for(int rt=0;rt<2;rt++)
#pragma unroll
      for(int ct=0;ct<8;ct++) acc1[rt][ct]=fz;
    for(int c=0;c<4;c++){                          // W1 chunks (2 ct each)
      const u16* Bw=&Wb[p%3][0];
      stage16k(wsu+phase_off(p+2), &Wb[(p+2)%3][0], wv, lane);
#pragma unroll
      for(int kt=0;kt<8;kt++)
#pragma unroll
        for(int i=0;i<2;i++){
          s16x8 bf=*(const s16x8*)(Bw + (((i*8+kt)*64+lane)<<3));
          acc1[0][c*2+i]=mfma16(af[0][kt],bf,acc1[0][c*2+i]);
          acc1[1][c*2+i]=mfma16(af[1][kt],bf,acc1[1][c*2+i]);
        }
      endph2(); p++;
    }
    {                                              // W2 phase
      const u16* Bw=&Wb[p%3][0];
      stage16k(wsu+phase_off(p+2), &Wb[(p+2)%3][0], wv, lane);
      const int pb=u*576;
      // layer-1 epilogue -> trb
#pragma unroll
      for(int rt=0;rt<2;rt++){
#pragma unroll
        for(int ct=0;ct<8;ct++){ float bb=bf2f(parAll[pb+ct*16+l15]);
#pragma unroll
          for(int r=0;r<4;r++) acc1[rt][ct][r]+=bb; }
        float mu[4],rs[4],nm[4];
        ln16<8>(&acc1[rt][0],1.f/128.f,mu,rs);
#pragma unroll
        for(int r=0;r<4;r++) nm[r]=-mu[r]*rs[r];
#pragma unroll
        for(int ct=0;ct<8;ct++){
          int col=ct*16+l15;
          float gv=bf2f(parAll[pb+128+col]), bev=bf2f(parAll[pb+256+col]);
#pragma unroll
          for(int r=0;r<4;r++){
            float vn=fmaf(acc1[rt][ct][r],rs[r],nm[r]);
            trbw[(rt*16+hq*4+r)*136+col]=f2bf(fmaxf(fmaf(vn,gv,bev),0.f));
          }
        }
      }
      lds_fence();
      s16x8 af2[2][4];
#pragma unroll
      for(int rt=0;rt<2;rt++)
#pragma unroll
        for(int kt=0;kt<4;kt++)
          af2[rt][kt]=*(const s16x8*)(trbw+(rt*16+l15)*136+kt*32+hq*8);
      f32x4 acc2[2][4];
#pragma unroll
      for(int rt=0;rt<2;rt++)
#pragma unroll
        for(int ct=0;ct<4;ct++) acc2[rt][ct]=fz;
#pragma unroll
      for(int kt=0;kt<4;kt++)
#pragma unroll
        for(int ct=0;ct<4;ct++){
          s16x8 bf=*(const s16x8*)(Bw + (((ct*4+kt)*64+lane)<<3));
          acc2[0][ct]=mfma16(af2[0][kt],bf,acc2[0][ct]);
          acc2[1][ct]=mfma16(af2[1][kt],bf,acc2[1][ct]);
        }
      // layer-2 epilogue + gated fusion: stays in registers
#pragma unroll
      for(int rt=0;rt<2;rt++){
#pragma unroll
        for(int ct=0;ct<4;ct++){ float bb=bf2f(parAll[pb+384+ct*16+l15]);
#pragma unroll
          for(int r=0;r<4;r++) acc2[rt][ct][r]+=bb; }
        float mu[4],rs[4],nm[4];
        ln16<4>(&acc2[rt][0],1.f/64.f,mu,rs);
#pragma unroll
        for(int r=0;r<4;r++) nm[r]=-mu[r]*rs[r];
        float g0v[4],g1v[4];
        if(u<8){
#pragma unroll
          for(int r=0;r<4;r++){ u32 gg=gateF[wv*32+rt*16+hq*4+r][u];
            g0v[r]=bf2f((u16)(gg&0xffffu)); g1v[r]=bf2f((u16)(gg>>16)); }
        } else if(u<11){
#pragma unroll
          for(int r=0;r<4;r++){ float m=(dm[rt][r]==u-8)?1.f:0.f; g0v[r]=m; g1v[r]=m; }
        } else {
          int q=u-11;
#pragma unroll
          for(int r=0;r<4;r++){
            g0v[r]=((dm[rt][r]&1)==q)?1.f:0.f;
            g1v[r]=(((dm[rt][r]+1)&1)==q)?1.f:0.f;
          }
        }
#pragma unroll
        for(int ct=0;ct<4;ct++){
          int col=ct*16+l15;
          float gv=bf2f(parAll[pb+448+col]), bev=bf2f(parAll[pb+512+col]);
#pragma unroll
          for(int r=0;r<4;r++){
            float vn=fmaf(acc2[rt][ct][r],rs[r],nm[r]);
            float o=fmaxf(fmaf(vn,gv,bev),0.f);
            fa0[rt][ct][r]=fmaf(g0v[r],o,fa0[rt][ct][r]);
            fa1[rt][ct][r]=fmaf(g1v[r],o,fa1[rt][ct][r]);
          }
        }
      }
      endph2(); p++;
    }
  }

  // ---- 6 dskip units: single layer, fused directly (no transpose, no h2) ----
  for(int j=0;j<6;j++){
    f32x4 a3[2][4];
#pragma unroll
    for(int rt=0;rt<2;rt++)
#pragma unroll
      for(int ct=0;ct<4;ct++) a3[rt][ct]=fz;
    for(int c=0;c<2;c++){
      const u16* Bw=&Wb[p%3][0];
      if(p+2<82) stage16k(wsu+phase_off(p+2), &Wb[(p+2)%3][0], wv, lane);
#pragma unroll
      for(int kt=0;kt<8;kt++)
#pragma unroll
        for(int i=0;i<2;i++){
          s16x8 bf=*(const s16x8*)(Bw + (((i*8+kt)*64+lane)<<3));
          a3[0][c*2+i]=mfma16(af[0][kt],bf,a3[0][c*2+i]);
          a3[1][c*2+i]=mfma16(af[1][kt],bf,a3[1][c*2+i]);
        }
      if(c==1){
        const int pb=PAR_DSK+j*192, dj=j%3;
#pragma unroll
        for(int rt=0;rt<2;rt++){
#pragma unroll
          for(int ct=0;ct<4;ct++){ float bb=bf2f(parAll[pb+ct*16+l15]);
#pragma unroll
            for(int r=0;r<4;r++) a3[rt][ct][r]+=bb; }
          float mu[4],rs[4],nm[4],mk[4];
          ln16<4>(&a3[rt][0],1.f/64.f,mu,rs);
#pragma unroll
          for(int r=0;r<4;r++){ nm[r]=-mu[r]*rs[r]; mk[r]=(dm[rt][r]==dj)?0.5f:0.f; }
#pragma unroll
          for(int ct=0;ct<4;ct++){
            int col=ct*16+l15;
            float gv=bf2f(parAll[pb+64+col]), bev=bf2f(parAll[pb+128+col]);
#pragma unroll
            for(int r=0;r<4;r++){
              float vn=fmaf(a3[rt][ct][r],rs[r],nm[r]);
              float o=fmaxf(fmaf(vn,gv,bev),0.f);
              if(j<3) fa0[rt][ct][r]=fmaf(mk[r],o,fa0[rt][ct][r]);
              else    fa1[rt][ct][r]=fmaf(mk[r],o,fa1[rt][ct][r]);
            }
          }
        }
      }
      endph2(); p++;
    }
  }

  // ---- transpose fused accumulators to A-frags (T=0 in cols 0..63, T=1 in 64..127) ----
#pragma unroll
  for(int rt=0;rt<2;rt++)
#pragma unroll
    for(int ct=0;ct<4;ct++)
#pragma unroll
      for(int r=0;r<4;r++){
        int rr=(rt*16+hq*4+r)*136 + ct*16+l15;
        trbw[rr]   =f2bf(fa0[rt][ct][r]);
        trbw[rr+64]=f2bf(fa1[rt][ct][r]);
      }
  lds_fence();
  s16x8 aft0[2][2], aft1[2][2];
#pragma unroll
  for(int rt=0;rt<2;rt++)
#pragma unroll
    for(int kt=0;kt<2;kt++){
      aft0[rt][kt]=*(const s16x8*)(trbw+(rt*16+l15)*136+kt*32+hq*8);
      aft1[rt][kt]=*(const s16x8*)(trbw+(rt*16+l15)*136+64+kt*32+hq*8);
    }

  // ---- towers (phases 79..81, 2 k6 per phase) ----
  for(int ph=0;ph<3;ph++){
    const u16* Bw=&Wb[p%3][0];
    if(p+2<82) stage16k(wsu+phase_off(p+2), &Wb[(p+2)%3][0], wv, lane);
#pragma unroll
    for(int s=0;s<2;s++){
      int k6=ph*2+s;
      int T0=(k6<3);
      int d=T0?k6:(k6-3);
      f32x4 ta[2][4];
#pragma unroll
      for(int rt=0;rt<2;rt++)
#pragma unroll
        for(int ct=0;ct<4;ct++) ta[rt][ct]=fz;
#pragma unroll
      for(int kt=0;kt<2;kt++)
#pragma unroll
        for(int ct=0;ct<4;ct++){
          s16x8 bf=*(const s16x8*)(Bw + s*4096 + (((ct*2+kt)*64+lane)<<3));
          if(T0){ ta[0][ct]=mfma16(aft0[0][kt],bf,ta[0][ct]); ta[1][ct]=mfma16(aft0[1][kt],bf,ta[1][ct]); }
          else  { ta[0][ct]=mfma16(aft1[0][kt],bf,ta[0][ct]); ta[1][ct]=mfma16(aft1[1][kt],bf,ta[1][ct]); }
        }
      const int pb=PAR_TOW+k6*256;
#pragma unroll
      for(int rt=0;rt<2;rt++){
#pragma unroll
        for(int ct=0;ct<4;ct++){ float bb=bf2f(parAll[pb+ct*16+l15]);
#pragma unroll
          for(int r=0;r<4;r++) ta[rt][ct][r]+=bb; }
        float mu[4],rs[4],nm[4];
        ln16<4>(&ta[rt][0],1.f/64.f,mu,rs);
#pragma unroll
        for(int r=0;r<4;r++) nm[r]=-mu[r]*rs[r];
        float pr[4]={0.f,0.f,0.f,0.f};
#pragma unroll
        for(int ct=0;ct<4;ct++){
          int col=ct*16+l15;
          float gv=bf2f(parAll[pb+64+col]), bev=bf2f(parAll[pb+128+col]), w2=bf2f(parAll[pb+192+col]);
#pragma unroll
          for(int r=0;r<4;r++){
            float vn=fmaf(ta[rt][ct][r],rs[r],nm[r]);
            float o=fmaxf(fmaf(vn,gv,bev),0.f);
            pr[r]=fmaf(o,w2,pr[r]);
          }
        }
#pragma unroll
        for(int m=1;m<16;m<<=1){
#pragma unroll
          for(int r=0;r<4;r++) pr[r]+=__shfl_xor(pr[r],m,16);
        }
        if(l15==0){
          float tb2=bf2f(parAll[PAR_TB2+k6]);
#pragma unroll
          for(int r=0;r<4;r++){
            if(dm[rt][r]==d){
              float sv=pr[r]+tb2;
              out[(size_t)(rowbase+rt*16+hq*4+r)*2 + (T0?0:1)] = 1.f/(1.f+__expf(-sv));
            }
          }
        }
      }
    }
    if(ph==0) endph2(); else if(ph==1) endph0();
    p++;
  }
}

// ============================ launcher ============================
extern "C" void kernel_launch(void* const* d_in, const int* in_sizes, int n_in,
                              void* d_out, int out_size, void* d_ws, size_t ws_size,
                              hipStream_t stream)
{
  const int*   x          =(const int*)  d_in[0];
  const float* emb_tables =(const float*)d_in[1];
  const float* skip_W     =(const float*)d_in[2];
  const float* skip_b     =(const float*)d_in[3];
  const float* skip_g     =(const float*)d_in[4];
  const float* skip_be    =(const float*)d_in[5];
  const float* shared_W   =(const float*)d_in[6];
  const float* shared_b   =(const float*)d_in[7];
  const float* slot_W     =(const float*)d_in[8];
  const float* slot_b     =(const float*)d_in[9];
  const float* star_W     =(const float*)d_in[10];
  const float* star_b     =(const float*)d_in[11];
  const float* star_g     =(const float*)d_in[12];
  const float* star_be    =(const float*)d_in[13];
  const float* dskip_W    =(const float*)d_in[14];
  const float* dskip_b    =(const float*)d_in[15];
  const float* dskip_g    =(const float*)d_in[16];
  const float* dskip_be   =(const float*)d_in[17];
  const float* exp_W1     =(const float*)d_in[18];
  const float* exp_b1     =(const float*)d_in[19];
  const float* exp_g1     =(const float*)d_in[20];
  const float* exp_be1    =(const float*)d_in[21];
  const float* exp_W2     =(const float*)d_in[22];
  const float* exp_b2     =(const float*)d_in[23];
  const float* exp_g2     =(const float*)d_in[24];
  const float* exp_be2    =(const float*)d_in[25];
  const float* dexp_W1    =(const float*)d_in[26];
  const float* dexp_b1    =(const float*)d_in[27];
  const float* dexp_g1    =(const float*)d_in[28];
  const float* dexp_be1   =(const float*)d_in[29];
  const float* dexp_W2    =(const float*)d_in[30];
  const float* dexp_b2    =(const float*)d_in[31];
  const float* dexp_g2    =(const float*)d_in[32];
  const float* dexp_be2   =(const float*)d_in[33];
  const float* texp_W1    =(const float*)d_in[34];
  const float* texp_b1    =(const float*)d_in[35];
  const float* texp_g1    =(const float*)d_in[36];
  const float* texp_be1   =(const float*)d_in[37];
  const float* texp_W2    =(const float*)d_in[38];
  const float* texp_b2    =(const float*)d_in[39];
  const float* texp_g2    =(const float*)d_in[40];
  const float* texp_be2   =(const float*)d_in[41];
  const float* gate_W     =(const float*)d_in[42];
  const float* gate_b     =(const float*)d_in[43];
  const float* tow_W1     =(const float*)d_in[44];
  const float* tow_b1     =(const float*)d_in[45];
  const float* tow_g      =(const float*)d_in[46];
  const float* tow_be     =(const float*)d_in[47];
  const float* tow_W2     =(const float*)d_in[48];
  const float* tow_b2     =(const float*)d_in[49];

  u16* wsu=(u16*)d_ws;
  float* out=(float*)d_out;

  k_pack<<<(OFF_BVEC+255)/256,256,0,stream>>>(skip_W,gate_W,
      exp_W1,dexp_W1,texp_W1,exp_W2,dexp_W2,texp_W2,dskip_W,tow_W1,wsu);
  k_packpar<<<46,256,0,stream>>>(
      exp_b1,exp_g1,exp_be1,exp_b2,exp_g2,exp_be2,
      dexp_b1,dexp_g1,dexp_be1,dexp_b2,dexp_g2,dexp_be2,
      texp_b1,texp_g1,texp_be1,texp_b2,texp_g2,texp_be2,
      dskip_b,dskip_g,dskip_be,gate_b,
      tow_b1,tow_g,tow_be,tow_W2,tow_b2,
      skip_b,skip_g,skip_be,star_b,star_g,star_be,wsu);
  k_fold<<<771,256,0,stream>>>(slot_W,shared_W,star_W,slot_b,shared_b,wsu);
  k_front<<<B_TOT/128,256,0,stream>>>(x,emb_tables,wsu);
  k_B<<<B_TOT/256,512,0,stream>>>(x,wsu,out);
}